// Round 2
// baseline (1311.729 us; speedup 1.0000x reference)
//
#include <hip/hip_runtime.h>
#include <hip/hip_bf16.h>

#define NNODES 100000
#define DIMN 128
#define NLAYERS 4

// ---------------- degree histogram ----------------
__global__ void k_hist(const int* __restrict__ src, const int* __restrict__ dst,
                       int* __restrict__ degOut, int* __restrict__ degIn, int E) {
    int i = blockIdx.x * blockDim.x + threadIdx.x;
    if (i < E) {
        atomicAdd(&degOut[src[i]], 1);
        atomicAdd(&degIn[dst[i]], 1);
    }
}

// ---------------- scan step 1: per-block sums of degIn ----------------
__global__ void k_bsum(const int* __restrict__ degIn, int* __restrict__ bsum, int N) {
    __shared__ int s[256];
    int t = threadIdx.x;
    int i = blockIdx.x * 256 + t;
    s[t] = (i < N) ? degIn[i] : 0;
    __syncthreads();
    for (int o = 128; o > 0; o >>= 1) {
        if (t < o) s[t] += s[t + o];
        __syncthreads();
    }
    if (t == 0) bsum[blockIdx.x] = s[0];
}

// ---------------- scan step 2: exclusive scan of block sums (NB <= 512) ----------------
__global__ void k_bscan(const int* __restrict__ bsum, int* __restrict__ boff, int NB) {
    __shared__ int s[512];
    int t = threadIdx.x;
    int v = (t < NB) ? bsum[t] : 0;
    s[t] = v;
    __syncthreads();
    for (int o = 1; o < 512; o <<= 1) {
        int x = (t >= o) ? s[t - o] : 0;
        __syncthreads();
        s[t] += x;
        __syncthreads();
    }
    if (t < NB) boff[t] = s[t] - v;  // exclusive
}

// ---------------- scan step 3: per-element exclusive scan + norms + row_ptr/cursor ----------
__global__ void k_scan3(const int* __restrict__ degIn, const int* __restrict__ degOut,
                        const int* __restrict__ boff, int* __restrict__ row_ptr,
                        int* __restrict__ cursor, float* __restrict__ norm_s,
                        float* __restrict__ norm_d, int N) {
    __shared__ int s[256];
    int t = threadIdx.x;
    int i = blockIdx.x * 256 + t;
    int v = (i < N) ? degIn[i] : 0;
    s[t] = v;
    __syncthreads();
    for (int o = 1; o < 256; o <<= 1) {
        int x = (t >= o) ? s[t - o] : 0;
        __syncthreads();
        s[t] += x;
        __syncthreads();
    }
    if (i < N) {
        int rp = boff[blockIdx.x] + s[t] - v;  // exclusive prefix
        row_ptr[i] = rp;
        cursor[i] = rp;
        float din = (float)v;
        float dout = (float)degOut[i];
        norm_d[i] = rsqrtf(fmaxf(din, 1.0f));
        norm_s[i] = rsqrtf(fmaxf(dout, 1.0f));
        if (i == N - 1) row_ptr[N] = rp + v;
    }
}

// ---------------- counting-sort scatter: edges bucketed by dst ----------------
__global__ void k_scatter(const int* __restrict__ src, const int* __restrict__ dst,
                          int* __restrict__ cursor, int* __restrict__ ssrc, int E) {
    int i = blockIdx.x * blockDim.x + threadIdx.x;
    if (i < E) {
        int d = dst[i];
        int pos = atomicAdd(&cursor[d], 1);
        ssrc[pos] = src[i];
    }
}

// ---------------- SpMM: one wave per dst node, CSR over sorted edges ----------------
__global__ __launch_bounds__(256) void k_spmm(const float* __restrict__ Hc,
                                              float* __restrict__ Agg,
                                              const int* __restrict__ row_ptr,
                                              const int* __restrict__ ssrc,
                                              const float* __restrict__ norm_s,
                                              const float* __restrict__ norm_d, int N) {
    int wave = (blockIdx.x * blockDim.x + threadIdx.x) >> 6;
    int lane = threadIdx.x & 63;
    if (wave >= N) return;
    int e0 = row_ptr[wave];
    int e1 = row_ptr[wave + 1];
    const float2* H2 = (const float2*)Hc;
    float2 acc;
    acc.x = 0.0f; acc.y = 0.0f;
    int e = e0;
    for (; e + 1 < e1; e += 2) {
        int sa = ssrc[e];
        int sb = ssrc[e + 1];
        float wa = norm_s[sa];
        float wb = norm_s[sb];
        float2 ha = H2[(size_t)sa * 64 + lane];
        float2 hb = H2[(size_t)sb * 64 + lane];
        acc.x += wa * ha.x + wb * hb.x;
        acc.y += wa * ha.y + wb * hb.y;
    }
    if (e < e1) {
        int sa = ssrc[e];
        float wa = norm_s[sa];
        float2 ha = H2[(size_t)sa * 64 + lane];
        acc.x += wa * ha.x;
        acc.y += wa * ha.y;
    }
    float nd = norm_d[wave];
    float2 o;
    o.x = acc.x * nd;
    o.y = acc.y * nd;
    ((float2*)Agg)[(size_t)wave * 64 + lane] = o;
}

// ---------------- embed GEMM: Hc = A @ W + b  (all f32) ----------------
__global__ __launch_bounds__(256) void k_embed(const float* __restrict__ A,
                                               const float* __restrict__ Wg,
                                               const float* __restrict__ bg,
                                               float* __restrict__ Hc, int N) {
    __shared__ float Wl[DIMN * DIMN];
    int tid = threadIdx.x;
#pragma unroll
    for (int it = 0; it < 16; ++it) {
        int idx = it * 1024 + tid * 4;
        *(float4*)(Wl + idx) = *(const float4*)(Wg + idx);
    }
    __syncthreads();
    int j = tid & 31;   // 32 col-groups of 4 columns
    int rg = tid >> 5;  // 8 row-groups
    int row0 = blockIdx.x * 64;
    const float4* Wl4 = (const float4*)Wl;
    float4 acc[8];
#pragma unroll
    for (int rr = 0; rr < 8; ++rr) acc[rr] = make_float4(0.f, 0.f, 0.f, 0.f);
    const float4* Arow[8];
    bool valid[8];
#pragma unroll
    for (int rr = 0; rr < 8; ++rr) {
        int r = row0 + rg + 8 * rr;
        valid[rr] = (r < N);
        int rc = (r < N) ? r : (N - 1);
        Arow[rr] = (const float4*)A + (size_t)rc * 32;
    }
    for (int k4 = 0; k4 < 32; ++k4) {
        float4 w0 = Wl4[(4 * k4 + 0) * 32 + j];
        float4 w1 = Wl4[(4 * k4 + 1) * 32 + j];
        float4 w2 = Wl4[(4 * k4 + 2) * 32 + j];
        float4 w3 = Wl4[(4 * k4 + 3) * 32 + j];
#pragma unroll
        for (int rr = 0; rr < 8; ++rr) {
            float4 a = Arow[rr][k4];
            acc[rr].x += a.x * w0.x + a.y * w1.x + a.z * w2.x + a.w * w3.x;
            acc[rr].y += a.x * w0.y + a.y * w1.y + a.z * w2.y + a.w * w3.y;
            acc[rr].z += a.x * w0.z + a.y * w1.z + a.z * w2.z + a.w * w3.z;
            acc[rr].w += a.x * w0.w + a.y * w1.w + a.z * w2.w + a.w * w3.w;
        }
    }
    float4 b4 = *(const float4*)(bg + 4 * j);
    float4* H4 = (float4*)Hc;
#pragma unroll
    for (int rr = 0; rr < 8; ++rr) {
        int r = row0 + rg + 8 * rr;
        if (valid[rr]) {
            float4 o;
            o.x = acc[rr].x + b4.x;
            o.y = acc[rr].y + b4.y;
            o.z = acc[rr].z + b4.z;
            o.w = acc[rr].w + b4.w;
            H4[(size_t)r * 32 + j] = o;
        }
    }
}

// ------- layer GEMM: tgt = Hc + relu(Agg@W + b)   (tgt = Hc, or d_out on last layer) ------
__global__ __launch_bounds__(256) void k_gemm(const float* __restrict__ Agg,
                                              const float* __restrict__ Wg,
                                              const float* __restrict__ bg,
                                              const float* __restrict__ Hc,
                                              float* __restrict__ tgt, int N) {
    __shared__ float Wl[DIMN * DIMN];
    int tid = threadIdx.x;
#pragma unroll
    for (int it = 0; it < 16; ++it) {
        int idx = it * 1024 + tid * 4;
        *(float4*)(Wl + idx) = *(const float4*)(Wg + idx);
    }
    __syncthreads();
    int j = tid & 31;
    int rg = tid >> 5;
    int row0 = blockIdx.x * 64;
    const float4* Wl4 = (const float4*)Wl;
    float4 acc[8];
#pragma unroll
    for (int rr = 0; rr < 8; ++rr) acc[rr] = make_float4(0.f, 0.f, 0.f, 0.f);
    const float4* Arow[8];
    bool valid[8];
#pragma unroll
    for (int rr = 0; rr < 8; ++rr) {
        int r = row0 + rg + 8 * rr;
        valid[rr] = (r < N);
        int rc = (r < N) ? r : (N - 1);
        Arow[rr] = (const float4*)Agg + (size_t)rc * 32;
    }
    for (int k4 = 0; k4 < 32; ++k4) {
        float4 w0 = Wl4[(4 * k4 + 0) * 32 + j];
        float4 w1 = Wl4[(4 * k4 + 1) * 32 + j];
        float4 w2 = Wl4[(4 * k4 + 2) * 32 + j];
        float4 w3 = Wl4[(4 * k4 + 3) * 32 + j];
#pragma unroll
        for (int rr = 0; rr < 8; ++rr) {
            float4 a = Arow[rr][k4];
            acc[rr].x += a.x * w0.x + a.y * w1.x + a.z * w2.x + a.w * w3.x;
            acc[rr].y += a.x * w0.y + a.y * w1.y + a.z * w2.y + a.w * w3.y;
            acc[rr].z += a.x * w0.z + a.y * w1.z + a.z * w2.z + a.w * w3.z;
            acc[rr].w += a.x * w0.w + a.y * w1.w + a.z * w2.w + a.w * w3.w;
        }
    }
    float4 b4 = *(const float4*)(bg + 4 * j);
    const float4* H4 = (const float4*)Hc;
    float4* T4 = (float4*)tgt;
#pragma unroll
    for (int rr = 0; rr < 8; ++rr) {
        int r = row0 + rg + 8 * rr;
        if (valid[rr]) {
            float4 z;
            z.x = fmaxf(acc[rr].x + b4.x, 0.f);
            z.y = fmaxf(acc[rr].y + b4.y, 0.f);
            z.z = fmaxf(acc[rr].z + b4.z, 0.f);
            z.w = fmaxf(acc[rr].w + b4.w, 0.f);
            float4 h = H4[(size_t)r * 32 + j];
            float4 o;
            o.x = h.x + z.x;
            o.y = h.y + z.y;
            o.z = h.z + z.z;
            o.w = h.w + z.w;
            T4[(size_t)r * 32 + j] = o;
        }
    }
}

static inline char* align256(char* p) {
    return (char*)(((uintptr_t)p + 255) & ~(uintptr_t)255);
}

extern "C" void kernel_launch(void* const* d_in, const int* in_sizes, int n_in,
                              void* d_out, int out_size, void* d_ws, size_t ws_size,
                              hipStream_t stream) {
    const float* h_in = (const float*)d_in[0];
    const int* src = (const int*)d_in[1];
    const int* dst = (const int*)d_in[2];
    const float* W_embed = (const float*)d_in[3];
    const float* b_embed = (const float*)d_in[4];
    const float* Ws = (const float*)d_in[5];
    const float* bs = (const float*)d_in[6];
    float* out = (float*)d_out;

    const int N = in_sizes[0] / DIMN;  // 100000
    const int E = in_sizes[1];         // 1600000
    const int NB = (N + 255) / 256;    // 391

    // -------- workspace carve --------
    char* w = (char*)d_ws;
    float* Hc = (float*)w;      w = align256(w + (size_t)N * DIMN * 4);
    float* Agg = (float*)w;     w = align256(w + (size_t)N * DIMN * 4);
    int* ssrc = (int*)w;        w = align256(w + (size_t)E * 4);
    int* row_ptr = (int*)w;     w = align256(w + (size_t)(N + 1) * 4);
    int* cursor = (int*)w;      w = align256(w + (size_t)N * 4);
    int* degOut = (int*)w;      // degOut and degIn contiguous for one memset
    int* degIn = degOut + N;    w = align256(w + (size_t)2 * N * 4);
    float* norm_s = (float*)w;  w = align256(w + (size_t)N * 4);
    float* norm_d = (float*)w;  w = align256(w + (size_t)N * 4);
    int* bsum = (int*)w;        w = align256(w + 512 * 4);
    int* boff = (int*)w;        w = align256(w + 512 * 4);

    // -------- CSR build (per launch; ws is re-poisoned every call) --------
    hipMemsetAsync(degOut, 0, (size_t)2 * N * 4, stream);

    int eb = (E + 255) / 256;
    k_hist<<<eb, 256, 0, stream>>>(src, dst, degOut, degIn, E);
    k_bsum<<<NB, 256, 0, stream>>>(degIn, bsum, N);
    k_bscan<<<1, 512, 0, stream>>>(bsum, boff, NB);
    k_scan3<<<NB, 256, 0, stream>>>(degIn, degOut, boff, row_ptr, cursor, norm_s, norm_d, N);
    k_scatter<<<eb, 256, 0, stream>>>(src, dst, cursor, ssrc, E);

    // -------- embed --------
    int gb = (N + 63) / 64;  // 64 rows per block
    k_embed<<<gb, 256, 0, stream>>>(h_in, W_embed, b_embed, Hc, N);

    // -------- layers --------
    int sb = (N + 3) / 4;  // 4 waves (nodes) per 256-thread block
    for (int l = 0; l < NLAYERS; ++l) {
        k_spmm<<<sb, 256, 0, stream>>>(Hc, Agg, row_ptr, ssrc, norm_s, norm_d, N);
        float* tgt = (l == NLAYERS - 1) ? out : Hc;
        k_gemm<<<gb, 256, 0, stream>>>(Agg, Ws + (size_t)l * DIMN * DIMN,
                                       bs + (size_t)l * DIMN, Hc, tgt, N);
    }
}

// Round 3
// 1054.718 us; speedup vs baseline: 1.2437x; 1.2437x over previous
//
#include <hip/hip_runtime.h>
#include <hip/hip_bf16.h>

#define NNODES 100000
#define DIMN 128
#define NLAYERS 4

__device__ inline float blo(unsigned int u) { return __uint_as_float(u << 16); }
__device__ inline float bhi(unsigned int u) { return __uint_as_float(u & 0xffff0000u); }
__device__ inline unsigned int f2bf(float f) {
    unsigned int u = __float_as_uint(f);
    return (u + 0x7fffu + ((u >> 16) & 1u)) >> 16;  // RTNE
}
__device__ inline unsigned int packbf(float a, float b) {
    return f2bf(a) | (f2bf(b) << 16);
}

// ---------------- degree histogram ----------------
__global__ void k_hist(const int* __restrict__ src, const int* __restrict__ dst,
                       int* __restrict__ degOut, int* __restrict__ degIn, int E) {
    int i = blockIdx.x * blockDim.x + threadIdx.x;
    if (i < E) {
        atomicAdd(&degOut[src[i]], 1);
        atomicAdd(&degIn[dst[i]], 1);
    }
}

// ---------------- scan step 1: per-block sums of degIn ----------------
__global__ void k_bsum(const int* __restrict__ degIn, int* __restrict__ bsum, int N) {
    __shared__ int s[256];
    int t = threadIdx.x;
    int i = blockIdx.x * 256 + t;
    s[t] = (i < N) ? degIn[i] : 0;
    __syncthreads();
    for (int o = 128; o > 0; o >>= 1) {
        if (t < o) s[t] += s[t + o];
        __syncthreads();
    }
    if (t == 0) bsum[blockIdx.x] = s[0];
}

// ---------------- scan step 2: exclusive scan of block sums (NB <= 512) ----------------
__global__ void k_bscan(const int* __restrict__ bsum, int* __restrict__ boff, int NB) {
    __shared__ int s[512];
    int t = threadIdx.x;
    int v = (t < NB) ? bsum[t] : 0;
    s[t] = v;
    __syncthreads();
    for (int o = 1; o < 512; o <<= 1) {
        int x = (t >= o) ? s[t - o] : 0;
        __syncthreads();
        s[t] += x;
        __syncthreads();
    }
    if (t < NB) boff[t] = s[t] - v;  // exclusive
}

// ---------------- scan step 3: per-element exclusive scan + norms + row_ptr/cursor ----------
__global__ void k_scan3(const int* __restrict__ degIn, const int* __restrict__ degOut,
                        const int* __restrict__ boff, int* __restrict__ row_ptr,
                        int* __restrict__ cursor, float* __restrict__ norm_s,
                        float* __restrict__ norm_d, int N) {
    __shared__ int s[256];
    int t = threadIdx.x;
    int i = blockIdx.x * 256 + t;
    int v = (i < N) ? degIn[i] : 0;
    s[t] = v;
    __syncthreads();
    for (int o = 1; o < 256; o <<= 1) {
        int x = (t >= o) ? s[t - o] : 0;
        __syncthreads();
        s[t] += x;
        __syncthreads();
    }
    if (i < N) {
        int rp = boff[blockIdx.x] + s[t] - v;  // exclusive prefix
        row_ptr[i] = rp;
        cursor[i] = rp;
        float din = (float)v;
        float dout = (float)degOut[i];
        norm_d[i] = rsqrtf(fmaxf(din, 1.0f));
        norm_s[i] = rsqrtf(fmaxf(dout, 1.0f));
        if (i == N - 1) row_ptr[N] = rp + v;
    }
}

// ---------------- counting-sort scatter: edges bucketed by dst ----------------
__global__ void k_scatter(const int* __restrict__ src, const int* __restrict__ dst,
                          int* __restrict__ cursor, int* __restrict__ ssrc, int E) {
    int i = blockIdx.x * blockDim.x + threadIdx.x;
    if (i < E) {
        int d = dst[i];
        int pos = atomicAdd(&cursor[d], 1);
        ssrc[pos] = src[i];
    }
}

// ---------------- SpMM over bf16 pre-scaled Hs: one wave per dst node ----------------
// Hs rows are 128 bf16 = 64 u32 = 256 B. Half-wave per edge: lanes 0-31 edge e,
// lanes 32-63 edge e+1; lane l5 covers dims [4*l5 .. 4*l5+3] via one 8 B load.
__global__ __launch_bounds__(256) void k_spmm(const unsigned int* __restrict__ Hs,
                                              float* __restrict__ Agg,
                                              const int* __restrict__ row_ptr,
                                              const int* __restrict__ ssrc,
                                              const float* __restrict__ norm_d, int N) {
    int wave = (blockIdx.x * blockDim.x + threadIdx.x) >> 6;
    int lane = threadIdx.x & 63;
    if (wave >= N) return;
    int e0 = row_ptr[wave];
    int e1 = row_ptr[wave + 1];
    int g = lane >> 5;   // which edge of the pair
    int l5 = lane & 31;  // dim group
    const uint2* H2 = (const uint2*)Hs;  // 8 B = 4 bf16
    float4 acc = make_float4(0.f, 0.f, 0.f, 0.f);

    int cnt = e1 - e0;
    int emain = e0 + (cnt & ~3);
    int e = e0;
    for (; e < emain; e += 4) {  // 4 edges per iter, 2 loads in flight per lane
        int s0 = ssrc[e + g];
        int s1 = ssrc[e + 2 + g];
        uint2 h0 = H2[(size_t)s0 * 32 + l5];
        uint2 h1 = H2[(size_t)s1 * 32 + l5];
        acc.x += blo(h0.x); acc.y += bhi(h0.x);
        acc.z += blo(h0.y); acc.w += bhi(h0.y);
        acc.x += blo(h1.x); acc.y += bhi(h1.x);
        acc.z += blo(h1.y); acc.w += bhi(h1.y);
    }
    for (; e < e1; e += 2) {  // tail: 1-3 edges
        int ee = e + g;
        int sc = ssrc[min(ee, e1 - 1)];
        uint2 hv = H2[(size_t)sc * 32 + l5];
        if (ee < e1) {
            acc.x += blo(hv.x); acc.y += bhi(hv.x);
            acc.z += blo(hv.y); acc.w += bhi(hv.y);
        }
    }
    // fold the two half-waves
    acc.x += __shfl_xor(acc.x, 32);
    acc.y += __shfl_xor(acc.y, 32);
    acc.z += __shfl_xor(acc.z, 32);
    acc.w += __shfl_xor(acc.w, 32);
    if (g == 0) {
        float nd = norm_d[wave];
        float4 o = make_float4(acc.x * nd, acc.y * nd, acc.z * nd, acc.w * nd);
        ((float4*)(Agg + (size_t)wave * DIMN))[l5] = o;
    }
}

// ------- unified GEMM: 512 thr, 128 rows/block, W (64 KiB) in LDS --------
// mode 0 (embed):  tgt = A@W + b
// mode 1 (layer):  tgt = Hres + relu(A@W + b)
// If Hs != null also emits bf16(out * norm_s) for the next spmm.
__global__ __launch_bounds__(512) void k_gemm(const float* __restrict__ A,
                                              const float* __restrict__ Wg,
                                              const float* __restrict__ bg,
                                              const float* __restrict__ Hres,
                                              float* __restrict__ tgt,
                                              const float* __restrict__ norm_s,
                                              unsigned int* __restrict__ Hs,
                                              int N, int mode) {
    __shared__ float Wl[DIMN * DIMN];
    int tid = threadIdx.x;
#pragma unroll
    for (int it = 0; it < 8; ++it) {  // 16384 floats / 512 thr = 8 float4 each
        int idx = it * 2048 + tid * 4;
        *(float4*)(Wl + idx) = *(const float4*)(Wg + idx);
    }
    __syncthreads();
    int j = tid & 31;   // 32 col-groups of 4 columns
    int rg = tid >> 5;  // 16 row groups
    int row0 = blockIdx.x * 128;
    const float4* Wl4 = (const float4*)Wl;
    float4 acc[8];
#pragma unroll
    for (int rr = 0; rr < 8; ++rr) acc[rr] = make_float4(0.f, 0.f, 0.f, 0.f);
    const float4* Arow[8];
    bool valid[8];
#pragma unroll
    for (int rr = 0; rr < 8; ++rr) {
        int r = row0 + rg + 16 * rr;
        valid[rr] = (r < N);
        int rc = (r < N) ? r : (N - 1);
        Arow[rr] = (const float4*)A + (size_t)rc * 32;
    }
    for (int k4 = 0; k4 < 32; ++k4) {
        float4 w0 = Wl4[(4 * k4 + 0) * 32 + j];
        float4 w1 = Wl4[(4 * k4 + 1) * 32 + j];
        float4 w2 = Wl4[(4 * k4 + 2) * 32 + j];
        float4 w3 = Wl4[(4 * k4 + 3) * 32 + j];
#pragma unroll
        for (int rr = 0; rr < 8; ++rr) {
            float4 a = Arow[rr][k4];
            acc[rr].x += a.x * w0.x + a.y * w1.x + a.z * w2.x + a.w * w3.x;
            acc[rr].y += a.x * w0.y + a.y * w1.y + a.z * w2.y + a.w * w3.y;
            acc[rr].z += a.x * w0.z + a.y * w1.z + a.z * w2.z + a.w * w3.z;
            acc[rr].w += a.x * w0.w + a.y * w1.w + a.z * w2.w + a.w * w3.w;
        }
    }
    float4 b4 = *(const float4*)(bg + 4 * j);
    const float4* H4 = (const float4*)Hres;
    float4* T4 = (float4*)tgt;
    uint2* Hs2 = (uint2*)Hs;
#pragma unroll
    for (int rr = 0; rr < 8; ++rr) {
        int r = row0 + rg + 16 * rr;
        if (valid[rr]) {
            float4 o;
            o.x = acc[rr].x + b4.x;
            o.y = acc[rr].y + b4.y;
            o.z = acc[rr].z + b4.z;
            o.w = acc[rr].w + b4.w;
            if (mode == 1) {
                o.x = fmaxf(o.x, 0.f); o.y = fmaxf(o.y, 0.f);
                o.z = fmaxf(o.z, 0.f); o.w = fmaxf(o.w, 0.f);
                float4 h = H4[(size_t)r * 32 + j];
                o.x += h.x; o.y += h.y; o.z += h.z; o.w += h.w;
            }
            T4[(size_t)r * 32 + j] = o;
            if (Hs) {
                float ns = norm_s[r];
                uint2 p;
                p.x = packbf(o.x * ns, o.y * ns);
                p.y = packbf(o.z * ns, o.w * ns);
                Hs2[(size_t)r * 32 + j] = p;
            }
        }
    }
}

static inline char* align256(char* p) {
    return (char*)(((uintptr_t)p + 255) & ~(uintptr_t)255);
}

extern "C" void kernel_launch(void* const* d_in, const int* in_sizes, int n_in,
                              void* d_out, int out_size, void* d_ws, size_t ws_size,
                              hipStream_t stream) {
    const float* h_in = (const float*)d_in[0];
    const int* src = (const int*)d_in[1];
    const int* dst = (const int*)d_in[2];
    const float* W_embed = (const float*)d_in[3];
    const float* b_embed = (const float*)d_in[4];
    const float* Ws = (const float*)d_in[5];
    const float* bs = (const float*)d_in[6];
    float* out = (float*)d_out;

    const int N = in_sizes[0] / DIMN;  // 100000
    const int E = in_sizes[1];         // 1600000
    const int NB = (N + 255) / 256;    // 391

    // -------- workspace carve --------
    char* w = (char*)d_ws;
    float* Hc = (float*)w;          w = align256(w + (size_t)N * DIMN * 4);
    float* Agg = (float*)w;         w = align256(w + (size_t)N * DIMN * 4);
    unsigned int* Hs = (unsigned int*)w; w = align256(w + (size_t)N * DIMN * 2);
    int* ssrc = (int*)w;            w = align256(w + (size_t)E * 4);
    int* row_ptr = (int*)w;         w = align256(w + (size_t)(N + 1) * 4);
    int* cursor = (int*)w;          w = align256(w + (size_t)N * 4);
    int* degOut = (int*)w;          // degOut and degIn contiguous for one memset
    int* degIn = degOut + N;        w = align256(w + (size_t)2 * N * 4);
    float* norm_s = (float*)w;      w = align256(w + (size_t)N * 4);
    float* norm_d = (float*)w;      w = align256(w + (size_t)N * 4);
    int* bsum = (int*)w;            w = align256(w + 512 * 4);
    int* boff = (int*)w;            w = align256(w + 512 * 4);

    // -------- CSR build (per launch; ws is re-poisoned every call) --------
    hipMemsetAsync(degOut, 0, (size_t)2 * N * 4, stream);

    int eb = (E + 255) / 256;
    k_hist<<<eb, 256, 0, stream>>>(src, dst, degOut, degIn, E);
    k_bsum<<<NB, 256, 0, stream>>>(degIn, bsum, N);
    k_bscan<<<1, 512, 0, stream>>>(bsum, boff, NB);
    k_scan3<<<NB, 256, 0, stream>>>(degIn, degOut, boff, row_ptr, cursor, norm_s, norm_d, N);
    k_scatter<<<eb, 256, 0, stream>>>(src, dst, cursor, ssrc, E);

    // -------- embed: Hc = h@We + be, Hs = bf16(Hc * norm_s) --------
    int gb = (N + 127) / 128;  // 128 rows per 512-thread block
    k_gemm<<<gb, 512, 0, stream>>>(h_in, W_embed, b_embed, nullptr, Hc, norm_s, Hs, N, 0);

    // -------- layers --------
    int sb = (N + 3) / 4;  // 4 waves (nodes) per 256-thread block
    for (int l = 0; l < NLAYERS; ++l) {
        k_spmm<<<sb, 256, 0, stream>>>(Hs, Agg, row_ptr, ssrc, norm_d, N);
        float* tgt = (l == NLAYERS - 1) ? out : Hc;
        unsigned int* hs_next = (l == NLAYERS - 1) ? nullptr : Hs;
        k_gemm<<<gb, 512, 0, stream>>>(Agg, Ws + (size_t)l * DIMN * DIMN,
                                       bs + (size_t)l * DIMN, Hc, tgt,
                                       norm_s, hs_next, N, 1);
    }
}